// Round 1
// baseline (128.437 us; speedup 1.0000x reference)
//
#include <hip/hip_runtime.h>
#include <math.h>

// Kuramoto: theta (1024x256), K (256x256, exactly symmetric), omega (256), K_global scalar.
// Key identities: sin(tj - ti) = sin tj cos ti - cos tj sin ti  -> two matvecs per step.
// K symmetric -> read K[j*N+i] (coalesced) in place of K[i*N+j].
// Intermediate wraps skipped (2pi-periodic dynamics, drift < 0.2 rad over 10 steps);
// only final wrap via atan2f matters for output.

constexpr int N      = 256;   // N_OSC
constexpr int B      = 1024;  // BATCH
constexpr int STEPS  = 10;
constexpr int R      = 4;     // batch rows per block (256 blocks -> 1/CU)
constexpr float DT   = 0.1f;

__global__ __launch_bounds__(N)
void kuramoto_kernel(const float* __restrict__ theta0,
                     const float* __restrict__ Kmat,
                     const float* __restrict__ omega,
                     const float* __restrict__ kglob,
                     float* __restrict__ theta_out,
                     float* __restrict__ coh_out)
{
    // sin/cos of the R rows packed per oscillator: one ds_read_b128 fetches all R.
    __shared__ float4 s4[N];
    __shared__ float4 c4[N];
    __shared__ float redS[R][4];
    __shared__ float redC[R][4];

    const int i  = threadIdx.x;        // oscillator index 0..255
    const int b0 = blockIdx.x * R;     // first batch row of this block

    float th[R];
#pragma unroll
    for (int r = 0; r < R; ++r)
        th[r] = theta0[(b0 + r) * N + i];

    const float om  = omega[i];
    const float kgn = kglob[0] / (float)N;   // K_global / n (exact /256)

    const float* kcol = Kmat + i;            // K[j][i] == K[i][j]

    for (int s = 0; s < STEPS; ++s) {
        float si[R], ci[R];
#pragma unroll
        for (int r = 0; r < R; ++r)
            sincosf(th[r], &si[r], &ci[r]);
        s4[i] = make_float4(si[0], si[1], si[2], si[3]);
        c4[i] = make_float4(ci[0], ci[1], ci[2], ci[3]);
        __syncthreads();

        float4 accS = make_float4(0.f, 0.f, 0.f, 0.f);
        float4 accC = make_float4(0.f, 0.f, 0.f, 0.f);
#pragma unroll 16
        for (int j = 0; j < N; ++j) {
            float  k  = kcol[j * N];     // coalesced, L2-resident
            float4 sv = s4[j];           // broadcast ds_read_b128
            float4 cv = c4[j];
            accS.x = fmaf(k, sv.x, accS.x);
            accS.y = fmaf(k, sv.y, accS.y);
            accS.z = fmaf(k, sv.z, accS.z);
            accS.w = fmaf(k, sv.w, accS.w);
            accC.x = fmaf(k, cv.x, accC.x);
            accC.y = fmaf(k, cv.y, accC.y);
            accC.z = fmaf(k, cv.z, accC.z);
            accC.w = fmaf(k, cv.w, accC.w);
        }
        __syncthreads();   // protect LDS before next step's writes

        const float sumS[R] = {accS.x, accS.y, accS.z, accS.w};
        const float sumC[R] = {accC.x, accC.y, accC.z, accC.w};
#pragma unroll
        for (int r = 0; r < R; ++r) {
            float coup = ci[r] * sumS[r] - si[r] * sumC[r];
            th[r] += DT * (om + kgn * coup);
        }
    }

    // Final wrap + theta output; sin/cos of wrapped value feed coherence.
    float sw[R], cw[R];
#pragma unroll
    for (int r = 0; r < R; ++r) {
        float s0, c0;
        sincosf(th[r], &s0, &c0);
        float w = atan2f(s0, c0);
        theta_out[(b0 + r) * N + i] = w;
        sincosf(w, &sw[r], &cw[r]);
    }

    // Block reduction: mean cos / mean sin over the 256 oscillators, per row.
    const int lane = i & 63, wv = i >> 6;
#pragma unroll
    for (int r = 0; r < R; ++r) {
        float s = sw[r], c = cw[r];
#pragma unroll
        for (int off = 32; off > 0; off >>= 1) {
            s += __shfl_down(s, off, 64);
            c += __shfl_down(c, off, 64);
        }
        if (lane == 0) { redS[r][wv] = s; redC[r][wv] = c; }
    }
    __syncthreads();
    if (i < R) {
        float s  = redS[i][0] + redS[i][1] + redS[i][2] + redS[i][3];
        float c  = redC[i][0] + redC[i][1] + redC[i][2] + redC[i][3];
        float sm = s * (1.0f / N);
        float cm = c * (1.0f / N);
        coh_out[b0 + i] = sqrtf(cm * cm + sm * sm);
    }
}

extern "C" void kernel_launch(void* const* d_in, const int* in_sizes, int n_in,
                              void* d_out, int out_size, void* d_ws, size_t ws_size,
                              hipStream_t stream) {
    const float* theta0 = (const float*)d_in[0];
    const float* Kmat   = (const float*)d_in[1];
    const float* omega  = (const float*)d_in[2];
    const float* kglob  = (const float*)d_in[3];

    float* theta_out = (float*)d_out;            // 1024*256 floats
    float* coh_out   = theta_out + B * N;        // then 1024 floats

    kuramoto_kernel<<<dim3(B / R), dim3(N), 0, stream>>>(
        theta0, Kmat, omega, kglob, theta_out, coh_out);
}

// Round 2
// 95.849 us; speedup vs baseline: 1.3400x; 1.3400x over previous
//
#include <hip/hip_runtime.h>
#include <math.h>

// Kuramoto via MFMA: coupling[b,i] = cos(th_i)*(K.sin th)_i - sin(th_i)*(K.cos th)_i.
// Two (16x256)x(256x256) bf16 GEMMs per step per block. K is EXACTLY symmetric
// (fp32 (K0+K0^T)/2), so B-frag loads K[j][i] as contiguous K[i][j] rows.
// K B-fragments resident in 128 VGPRs across all 10 steps -> zero K re-reads.
// theta lives in MFMA C/D layout registers: row b = quad*4+reg, col i = 64w+16t+(lane&15).
// Verified gfx950 layouts: A[m=lane&15][k=quad*8+j]; B[k=quad*8+j][n=lane&15];
// D[row=quad*4+reg][col=lane&15]. bf16 rounding error -> theta err ~1e-5 << 6.3e-2 thr.

typedef __attribute__((ext_vector_type(8))) short short8;
typedef __attribute__((ext_vector_type(4))) float f32x4;

constexpr int N     = 256;   // oscillators
constexpr int RB    = 16;    // batch rows per block (MFMA M)
constexpr int STEPS = 10;
constexpr int LDST  = 264;   // staged row stride in bf16 elems (256 + 8 pad, mult of 8 for 16B align)
constexpr float DT  = 0.1f;

__device__ __forceinline__ unsigned short f2bf(float f) {
    unsigned u = __float_as_uint(f);
    return (unsigned short)((u + 0x8000u) >> 16);   // round-half-up to bf16
}

__global__ __launch_bounds__(256, 1)
void kuramoto_mfma(const float* __restrict__ theta0,
                   const float* __restrict__ Kmat,
                   const float* __restrict__ omega,
                   const float* __restrict__ kglob,
                   float* __restrict__ theta_out,
                   float* __restrict__ coh_out)
{
    __shared__ __align__(16) unsigned short S_lds[RB][LDST];
    __shared__ __align__(16) unsigned short C_lds[RB][LDST];
    __shared__ float redS[RB][4];
    __shared__ float redC[RB][4];

    const int tid  = threadIdx.x;
    const int w    = tid >> 6;      // wave 0..3 -> col range [64w, 64w+64)
    const int lane = tid & 63;
    const int quad = lane >> 4;
    const int l15  = lane & 15;
    const int b0   = blockIdx.x * RB;

    const float kgn = kglob[0] * (1.0f / (float)N);

    // ---- one-time: K B-fragments into registers (K symmetric -> row reads) ----
    // frag (t,c): lane holds B[k=quad*8+jj][n=l15] = K[32c+quad*8+jj][i] = K[i][32c+quad*8+jj]
    short8 kf[4][8];
#pragma unroll
    for (int t = 0; t < 4; ++t) {
        const int i = 64 * w + 16 * t + l15;
        const float* kr = Kmat + (size_t)i * N + 8 * quad;
#pragma unroll
        for (int c = 0; c < 8; ++c) {
            float4 lo = *(const float4*)(kr + 32 * c);
            float4 hi = *(const float4*)(kr + 32 * c + 4);
            short8 v;
            v[0] = (short)f2bf(lo.x); v[1] = (short)f2bf(lo.y);
            v[2] = (short)f2bf(lo.z); v[3] = (short)f2bf(lo.w);
            v[4] = (short)f2bf(hi.x); v[5] = (short)f2bf(hi.y);
            v[6] = (short)f2bf(hi.z); v[7] = (short)f2bf(hi.w);
            kf[t][c] = v;
        }
    }

    // ---- theta in C/D-layout registers: thv[t][r] = theta[b0+4*quad+r][64w+16t+l15] ----
    float thv[4][4];
    float om[4];
#pragma unroll
    for (int t = 0; t < 4; ++t) {
        const int i = 64 * w + 16 * t + l15;
        om[t] = omega[i];
#pragma unroll
        for (int r = 0; r < 4; ++r)
            thv[t][r] = theta0[(size_t)(b0 + 4 * quad + r) * N + i];
    }

    unsigned scpk[4][4];   // packed bf16: sin in low16, cos in high16

    for (int s = 0; s < STEPS; ++s) {
        // stage sin/cos (bf16) to LDS in [b][j] layout
#pragma unroll
        for (int t = 0; t < 4; ++t) {
            const int j = 64 * w + 16 * t + l15;
#pragma unroll
            for (int r = 0; r < 4; ++r) {
                float sv, cv;
                sincosf(thv[t][r], &sv, &cv);
                unsigned short sb = f2bf(sv), cb = f2bf(cv);
                scpk[t][r] = (unsigned)sb | ((unsigned)cb << 16);
                S_lds[4 * quad + r][j] = sb;
                C_lds[4 * quad + r][j] = cb;
            }
        }
        __syncthreads();

        // GEMM: GS = S*K, GC = C*K (K B-frags in regs)
        f32x4 aS[4], aC[4];
#pragma unroll
        for (int t = 0; t < 4; ++t) {
            aS[t] = (f32x4){0.f, 0.f, 0.f, 0.f};
            aC[t] = (f32x4){0.f, 0.f, 0.f, 0.f};
        }
#pragma unroll
        for (int c = 0; c < 8; ++c) {
            short8 As = *(const short8*)&S_lds[l15][32 * c + 8 * quad];
            short8 Ac = *(const short8*)&C_lds[l15][32 * c + 8 * quad];
#pragma unroll
            for (int t = 0; t < 4; ++t) {
                aS[t] = __builtin_amdgcn_mfma_f32_16x16x32_bf16(As, kf[t][c], aS[t], 0, 0, 0);
                aC[t] = __builtin_amdgcn_mfma_f32_16x16x32_bf16(Ac, kf[t][c], aC[t], 0, 0, 0);
            }
        }
        __syncthreads();   // all A-reads done before next step's staging writes

        // theta update, fully in registers (C/D layout matches thv)
#pragma unroll
        for (int t = 0; t < 4; ++t) {
#pragma unroll
            for (int r = 0; r < 4; ++r) {
                float sv = __uint_as_float(scpk[t][r] << 16);
                float cv = __uint_as_float(scpk[t][r] & 0xffff0000u);
                float coup = cv * aS[t][r] - sv * aC[t][r];
                thv[t][r] = fmaf(DT, fmaf(kgn, coup, om[t]), thv[t][r]);
            }
        }
    }

    // ---- epilogue: wrap, store theta, coherence ----
    float sumS[4] = {0.f, 0.f, 0.f, 0.f};   // per r, summed over this lane's 4 tiles
    float sumC[4] = {0.f, 0.f, 0.f, 0.f};
#pragma unroll
    for (int t = 0; t < 4; ++t) {
        const int i = 64 * w + 16 * t + l15;
#pragma unroll
        for (int r = 0; r < 4; ++r) {
            float s0, c0;
            sincosf(thv[t][r], &s0, &c0);
            float wv = atan2f(s0, c0);
            theta_out[(size_t)(b0 + 4 * quad + r) * N + i] = wv;
            sumS[r] += s0;   // == sin(wrapped) up to 1 ulp
            sumC[r] += c0;
        }
    }
    // reduce across the 16 lanes of each quad (same batch rows)
#pragma unroll
    for (int r = 0; r < 4; ++r) {
#pragma unroll
        for (int off = 1; off <= 8; off <<= 1) {
            sumS[r] += __shfl_xor(sumS[r], off, 64);
            sumC[r] += __shfl_xor(sumC[r], off, 64);
        }
    }
    if (l15 == 0) {
#pragma unroll
        for (int r = 0; r < 4; ++r) {
            redS[4 * quad + r][w] = sumS[r];
            redC[4 * quad + r][w] = sumC[r];
        }
    }
    __syncthreads();
    if (tid < RB) {
        float S = redS[tid][0] + redS[tid][1] + redS[tid][2] + redS[tid][3];
        float C = redC[tid][0] + redC[tid][1] + redC[tid][2] + redC[tid][3];
        float sm = S * (1.0f / (float)N);
        float cm = C * (1.0f / (float)N);
        coh_out[b0 + tid] = sqrtf(sm * sm + cm * cm);
    }
}

extern "C" void kernel_launch(void* const* d_in, const int* in_sizes, int n_in,
                              void* d_out, int out_size, void* d_ws, size_t ws_size,
                              hipStream_t stream) {
    const float* theta0 = (const float*)d_in[0];
    const float* Kmat   = (const float*)d_in[1];
    const float* omega  = (const float*)d_in[2];
    const float* kglob  = (const float*)d_in[3];

    float* theta_out = (float*)d_out;          // 1024*256
    float* coh_out   = theta_out + 1024 * N;   // then 1024

    kuramoto_mfma<<<dim3(1024 / RB), dim3(256), 0, stream>>>(
        theta0, Kmat, omega, kglob, theta_out, coh_out);
}

// Round 3
// 76.074 us; speedup vs baseline: 1.6883x; 1.2599x over previous
//
#include <hip/hip_runtime.h>
#include <math.h>

// Kuramoto via MFMA, round 3: 8 waves/block (2 waves/SIMD) for latency hiding,
// __sincosf (HW v_sin/v_cos) in the step loop, XOR-swizzled bf16 staging
// (zero bank conflicts), double-buffered LDS -> one barrier per step.
//
// coupling[b,i] = cos(th_i)*(K.sin th)_i - sin(th_i)*(K.cos th)_i
// K exactly symmetric -> B-frags load K rows contiguously; resident in VGPRs.
// Layouts (verified on gfx950, R2 passed): A[m=lane&15][k=quad*8+j];
// B[k=quad*8+j][n=lane&15]; D[row=quad*4+reg][col=lane&15].
// Accuracy floor is bf16 staging (absmax ~= 1 bf16 ulp = 0.0156 << 0.0628 thr);
// __sincosf (~1e-5 abs) and rint-wrap are invisible under it.

typedef __attribute__((ext_vector_type(8))) short short8;
typedef __attribute__((ext_vector_type(4))) float f32x4;

constexpr int N       = 256;   // oscillators
constexpr int RB      = 16;    // batch rows per block (MFMA M)
constexpr int STEPS   = 10;
constexpr int WAVES   = 8;     // 2 col-tiles of 16 per wave
constexpr int THREADS = WAVES * 64;
constexpr float DT    = 0.1f;
constexpr float TWO_PI     = 6.28318530717958648f;
constexpr float INV_TWO_PI = 0.15915494309189535f;

__device__ __forceinline__ unsigned short f2bf(float f) {
    unsigned u = __float_as_uint(f);
    return (unsigned short)((u + 0x8000u) >> 16);   // round-half-up to bf16
}

__global__ __launch_bounds__(THREADS, 2)
void kuramoto_mfma(const float* __restrict__ theta0,
                   const float* __restrict__ Kmat,
                   const float* __restrict__ omega,
                   const float* __restrict__ kglob,
                   float* __restrict__ theta_out,
                   float* __restrict__ coh_out)
{
    // [buf][S=0/C=1][row][swizzled col]; row stride 256 shorts = 128 dwords = 0 mod 32 banks.
    // Swizzle: 8-short group g stored at g ^ (row&7) -> uniform bank coverage for
    // the A-frag b128 reads (each of 8 bank-quads hit by exactly 8 lanes).
    __shared__ __align__(16) unsigned short SC[2][2][RB][N];
    __shared__ float redS[RB][WAVES];
    __shared__ float redC[RB][WAVES];

    const int tid  = threadIdx.x;
    const int wv   = tid >> 6;      // wave 0..7 -> col slab [32*wv, 32*wv+32)
    const int lane = tid & 63;
    const int q    = lane >> 4;     // quad
    const int l15  = lane & 15;
    const int b0   = blockIdx.x * RB;

    const float kgn = kglob[0] * (1.0f / (float)N);

    // ---- K B-fragments resident in VGPRs (symmetry -> contiguous row reads) ----
    short8 kf[2][8];
#pragma unroll
    for (int t = 0; t < 2; ++t) {
        const int n = 32 * wv + 16 * t + l15;
        const float* kr = Kmat + (size_t)n * N + 8 * q;
#pragma unroll
        for (int c = 0; c < 8; ++c) {
            float4 lo = *(const float4*)(kr + 32 * c);
            float4 hi = *(const float4*)(kr + 32 * c + 4);
            short8 v;
            v[0] = (short)f2bf(lo.x); v[1] = (short)f2bf(lo.y);
            v[2] = (short)f2bf(lo.z); v[3] = (short)f2bf(lo.w);
            v[4] = (short)f2bf(hi.x); v[5] = (short)f2bf(hi.y);
            v[6] = (short)f2bf(hi.z); v[7] = (short)f2bf(hi.w);
            kf[t][c] = v;
        }
    }

    // ---- theta in C/D layout: thv[t][r] = theta[b0+4q+r][32wv+16t+l15] ----
    float thv[2][4], om[2];
#pragma unroll
    for (int t = 0; t < 2; ++t) {
        const int col = 32 * wv + 16 * t + l15;
        om[t] = omega[col];
#pragma unroll
        for (int r = 0; r < 4; ++r)
            thv[t][r] = theta0[(size_t)(b0 + 4 * q + r) * N + col];
    }

    float sv[2][4], cv[2][4];

    for (int s = 0; s < STEPS; ++s) {
        const int buf = s & 1;
        // ---- stage sin/cos (bf16, swizzled) ----
#pragma unroll
        for (int t = 0; t < 2; ++t) {
            const int j = 32 * wv + 16 * t + l15;
            const int g = j >> 3, o = j & 7;
#pragma unroll
            for (int r = 0; r < 4; ++r) {
                __sincosf(thv[t][r], &sv[t][r], &cv[t][r]);
                const int row  = 4 * q + r;
                const int phys = ((g ^ (row & 7)) << 3) + o;
                SC[buf][0][row][phys] = f2bf(sv[t][r]);
                SC[buf][1][row][phys] = f2bf(cv[t][r]);
            }
        }
        __syncthreads();   // single barrier/step: double buffer covers WAR

        // ---- GEMM: D_S = S*K, D_C = C*K ----
        f32x4 aS[2], aC[2];
#pragma unroll
        for (int t = 0; t < 2; ++t) {
            aS[t] = (f32x4){0.f, 0.f, 0.f, 0.f};
            aC[t] = (f32x4){0.f, 0.f, 0.f, 0.f};
        }
#pragma unroll
        for (int c = 0; c < 8; ++c) {
            const int phys = ((4 * c + q) ^ (l15 & 7)) << 3;
            short8 As = *(const short8*)&SC[buf][0][l15][phys];
            short8 Ac = *(const short8*)&SC[buf][1][l15][phys];
#pragma unroll
            for (int t = 0; t < 2; ++t) {
                aS[t] = __builtin_amdgcn_mfma_f32_16x16x32_bf16(As, kf[t][c], aS[t], 0, 0, 0);
                aC[t] = __builtin_amdgcn_mfma_f32_16x16x32_bf16(Ac, kf[t][c], aC[t], 0, 0, 0);
            }
        }

        // ---- theta update (registers, C/D layout) ----
#pragma unroll
        for (int t = 0; t < 2; ++t) {
#pragma unroll
            for (int r = 0; r < 4; ++r) {
                float coup = cv[t][r] * aS[t][r] - sv[t][r] * aC[t][r];
                thv[t][r] = fmaf(DT, fmaf(kgn, coup, om[t]), thv[t][r]);
            }
        }
    }

    // ---- epilogue: wrap to (-pi,pi], store theta, coherence ----
    float sumS[4] = {0.f, 0.f, 0.f, 0.f};
    float sumC[4] = {0.f, 0.f, 0.f, 0.f};
#pragma unroll
    for (int t = 0; t < 2; ++t) {
        const int col = 32 * wv + 16 * t + l15;
#pragma unroll
        for (int r = 0; r < 4; ++r) {
            float th = thv[t][r];
            float s0, c0;
            __sincosf(th, &s0, &c0);
            float w = fmaf(-TWO_PI, rintf(th * INV_TWO_PI), th);  // == atan2(sin,cos)
            theta_out[(size_t)(b0 + 4 * q + r) * N + col] = w;
            sumS[r] += s0;
            sumC[r] += c0;
        }
    }
    // sum over the 16 lanes of the quad (same batch rows), then across waves via LDS
#pragma unroll
    for (int r = 0; r < 4; ++r) {
#pragma unroll
        for (int off = 1; off <= 8; off <<= 1) {
            sumS[r] += __shfl_xor(sumS[r], off, 64);
            sumC[r] += __shfl_xor(sumC[r], off, 64);
        }
    }
    if (l15 == 0) {
#pragma unroll
        for (int r = 0; r < 4; ++r) {
            redS[4 * q + r][wv] = sumS[r];
            redC[4 * q + r][wv] = sumC[r];
        }
    }
    __syncthreads();
    if (tid < RB) {
        float S = 0.f, C = 0.f;
#pragma unroll
        for (int k = 0; k < WAVES; ++k) { S += redS[tid][k]; C += redC[tid][k]; }
        float sm = S * (1.0f / (float)N);
        float cm = C * (1.0f / (float)N);
        coh_out[b0 + tid] = sqrtf(sm * sm + cm * cm);
    }
}

extern "C" void kernel_launch(void* const* d_in, const int* in_sizes, int n_in,
                              void* d_out, int out_size, void* d_ws, size_t ws_size,
                              hipStream_t stream) {
    const float* theta0 = (const float*)d_in[0];
    const float* Kmat   = (const float*)d_in[1];
    const float* omega  = (const float*)d_in[2];
    const float* kglob  = (const float*)d_in[3];

    float* theta_out = (float*)d_out;          // 1024*256
    float* coh_out   = theta_out + 1024 * N;   // then 1024

    kuramoto_mfma<<<dim3(1024 / RB), dim3(THREADS), 0, stream>>>(
        theta0, Kmat, omega, kglob, theta_out, coh_out);
}

// Round 4
// 75.194 us; speedup vs baseline: 1.7081x; 1.0117x over previous
//
#include <hip/hip_runtime.h>
#include <math.h>

// Kuramoto via fp8 MFMA, round 4: TRANSPOSED GEMM  G^T = K · S^T.
//   A = K (fp8, resident in VGPR frags, loaded once; m = oscillator)
//   B = staged sin/cos (fp8, k = osc j contiguous per lane, n = batch)
//   D[row=q*4+r][col=l15]: row -> 4 consecutive OSCILLATORS, col -> batch.
// => each thread's theta covers 4 consecutive osc of one batch row, so the
//    next step's staging write is ONE packed b64 (sin+cos interleaved) per
//    tile instead of 16 scalar b16 writes.  fp8 staging halves LDS reads:
//    one b128 per k-iter serves BOTH GEMMs (S and C interleaved in 16B units).
// Error budget: fp8 (e4m3) on sin/cos/K -> per-step dtheta err ~1e-5..1.5e-4
// total, far under the bf16-comparison floor (absmax pinned at 1 bf16 ulp).
// k-slot permutation of fp8 frags is self-consistent between A and B, and
// m/n = lane&15, D row=q*4+reg were HW-verified by rounds 2-3 passing.

typedef __attribute__((ext_vector_type(4))) float f32x4;

constexpr int N       = 256;   // oscillators
constexpr int RB      = 16;    // batch rows per block
constexpr int STEPS   = 10;
constexpr int WAVES   = 8;     // 2 m-tiles (osc) of 16 per wave
constexpr int THREADS = WAVES * 64;
constexpr float DT    = 0.1f;
constexpr float TWO_PI     = 6.28318530717958648f;
constexpr float INV_TWO_PI = 0.15915494309189535f;

__global__ __launch_bounds__(THREADS, 2)
void kuramoto_fp8(const float* __restrict__ theta0,
                  const float* __restrict__ Kmat,
                  const float* __restrict__ omega,
                  const float* __restrict__ kglob,
                  float* __restrict__ theta_out,
                  float* __restrict__ coh_out)
{
    // Staging: [buf][batch b][32 units of 16B]. Unit = [S0-3 | C0-3 | S4-7 | C4-7]
    // for an 8-osc k-chunk. Unit index XOR-swizzled by b -> uniform banks for
    // both the b64 writes and the b128 reads.
    __shared__ __align__(16) unsigned char SC[2][RB][512];
    __shared__ float redS[RB][WAVES], redC[RB][WAVES];

    const int tid  = threadIdx.x;
    const int wv   = tid >> 6;      // wave 0..7 -> osc slab [32*wv, 32*wv+32)
    const int lane = tid & 63;
    const int q    = lane >> 4;     // quad
    const int l15  = lane & 15;     // A-frag m / B-frag n (batch) / D col
    const int b0   = blockIdx.x * RB;

    const float kgn = kglob[0] * (1.0f / 256.0f);

    // ---- K resident as fp8 A-frags: kf[t][c] = A[m=l15][k=32c+8q+jj], tile 32wv+16t ----
    long kf[2][8];
#pragma unroll
    for (int t = 0; t < 2; ++t) {
        const int i = 32 * wv + 16 * t + l15;
        const float* kr = Kmat + (size_t)i * N + 8 * q;
#pragma unroll
        for (int c = 0; c < 8; ++c) {
            float4 lo = *(const float4*)(kr + 32 * c);
            float4 hi = *(const float4*)(kr + 32 * c + 4);
            int w0 = __builtin_amdgcn_cvt_pk_fp8_f32(lo.x, lo.y, 0, false);
            w0     = __builtin_amdgcn_cvt_pk_fp8_f32(lo.z, lo.w, w0, true);
            int w1 = __builtin_amdgcn_cvt_pk_fp8_f32(hi.x, hi.y, 0, false);
            w1     = __builtin_amdgcn_cvt_pk_fp8_f32(hi.z, hi.w, w1, true);
            kf[t][c] = (long)(unsigned)w0 | ((long)w1 << 32);
        }
    }

    // ---- theta in (transposed) D layout: thv[t][r] = theta[b0+l15][32wv+16t+4q+r] ----
    float thv[2][4], om[2][4];
#pragma unroll
    for (int t = 0; t < 2; ++t)
#pragma unroll
        for (int r = 0; r < 4; ++r) {
            const int i = 32 * wv + 16 * t + 4 * q + r;
            om[t][r]  = omega[i];
            thv[t][r] = theta0[(size_t)(b0 + l15) * N + i];
        }

    float sv[2][4], cv[2][4];

    for (int s = 0; s < STEPS; ++s) {
        const int buf = s & 1;
        // ---- stage: sincos -> fp8 pack -> one b64 write per tile ----
#pragma unroll
        for (int t = 0; t < 2; ++t) {
#pragma unroll
            for (int r = 0; r < 4; ++r)
                __sincosf(thv[t][r], &sv[t][r], &cv[t][r]);
            int spk = __builtin_amdgcn_cvt_pk_fp8_f32(sv[t][0], sv[t][1], 0, false);
            spk     = __builtin_amdgcn_cvt_pk_fp8_f32(sv[t][2], sv[t][3], spk, true);
            int cpk = __builtin_amdgcn_cvt_pk_fp8_f32(cv[t][0], cv[t][1], 0, false);
            cpk     = __builtin_amdgcn_cvt_pk_fp8_f32(cv[t][2], cv[t][3], cpk, true);
            const int g = 8 * wv + 4 * t + q;        // 4-osc group index 0..63
            const int u = (g >> 1) ^ l15;            // swizzled 16B unit
            int2 val; val.x = spk; val.y = cpk;
            *(int2*)&SC[buf][l15][16 * u + 8 * (g & 1)] = val;
        }
        __syncthreads();   // single barrier/step; double buffer covers WAR

        // ---- GEMMs: D_S = K*S^T, D_C = K*C^T (one b128 read feeds both) ----
        f32x4 aS[2], aC[2];
#pragma unroll
        for (int t = 0; t < 2; ++t) {
            aS[t] = (f32x4){0.f, 0.f, 0.f, 0.f};
            aC[t] = (f32x4){0.f, 0.f, 0.f, 0.f};
        }
#pragma unroll
        for (int c = 0; c < 8; ++c) {
            const int uu = (4 * c + q) ^ l15;
            int4 vvv = *(const int4*)&SC[buf][l15][16 * uu];
            long Bs = (long)(unsigned)vvv.x | ((long)vvv.z << 32);
            long Bc = (long)(unsigned)vvv.y | ((long)vvv.w << 32);
#pragma unroll
            for (int t = 0; t < 2; ++t) {
                aS[t] = __builtin_amdgcn_mfma_f32_16x16x32_fp8_fp8(kf[t][c], Bs, aS[t], 0, 0, 0);
                aC[t] = __builtin_amdgcn_mfma_f32_16x16x32_fp8_fp8(kf[t][c], Bc, aC[t], 0, 0, 0);
            }
        }

        // ---- theta update (registers) ----
#pragma unroll
        for (int t = 0; t < 2; ++t)
#pragma unroll
            for (int r = 0; r < 4; ++r) {
                float coup = cv[t][r] * aS[t][r] - sv[t][r] * aC[t][r];
                thv[t][r] = fmaf(DT, fmaf(kgn, coup, om[t][r]), thv[t][r]);
            }
    }

    // ---- epilogue: wrap to (-pi,pi], store theta, per-batch coherence ----
    float ps = 0.f, pc = 0.f;
#pragma unroll
    for (int t = 0; t < 2; ++t)
#pragma unroll
        for (int r = 0; r < 4; ++r) {
            float th = thv[t][r];
            float s0, c0;
            __sincosf(th, &s0, &c0);
            float w = fmaf(-TWO_PI, rintf(th * INV_TWO_PI), th);  // principal wrap
            theta_out[(size_t)(b0 + l15) * N + 32 * wv + 16 * t + 4 * q + r] = w;
            ps += s0; pc += c0;
        }
    // sum across the 4 quads (same batch row l15), then across waves via LDS
    ps += __shfl_xor(ps, 16, 64);  pc += __shfl_xor(pc, 16, 64);
    ps += __shfl_xor(ps, 32, 64);  pc += __shfl_xor(pc, 32, 64);
    if (q == 0) { redS[l15][wv] = ps; redC[l15][wv] = pc; }
    __syncthreads();
    if (tid < RB) {
        float S = 0.f, C = 0.f;
#pragma unroll
        for (int k = 0; k < WAVES; ++k) { S += redS[tid][k]; C += redC[tid][k]; }
        float sm = S * (1.0f / 256.0f);
        float cm = C * (1.0f / 256.0f);
        coh_out[b0 + tid] = sqrtf(sm * sm + cm * cm);
    }
}

extern "C" void kernel_launch(void* const* d_in, const int* in_sizes, int n_in,
                              void* d_out, int out_size, void* d_ws, size_t ws_size,
                              hipStream_t stream) {
    const float* theta0 = (const float*)d_in[0];
    const float* Kmat   = (const float*)d_in[1];
    const float* omega  = (const float*)d_in[2];
    const float* kglob  = (const float*)d_in[3];

    float* theta_out = (float*)d_out;          // 1024*256
    float* coh_out   = theta_out + 1024 * N;   // then 1024

    kuramoto_fp8<<<dim3(1024 / RB), dim3(THREADS), 0, stream>>>(
        theta0, Kmat, omega, kglob, theta_out, coh_out);
}